// Round 10
// baseline (307.932 us; speedup 1.0000x reference)
//
#include <hip/hip_runtime.h>

constexpr int Nn   = 50000;
constexpr int Ee   = 800000;
constexpr int INC  = 64;
constexpr int HC   = 128;
constexpr int ECc  = 16;
constexpr int MLPc = 256;
constexpr int NCc  = 32;
constexpr int Gg   = 512;
constexpr int Mpad = 50048;          // 391*128

typedef __attribute__((ext_vector_type(8))) short short8;
typedef __attribute__((ext_vector_type(4))) short short4v;
typedef __attribute__((ext_vector_type(4))) float f32x4;

__device__ __forceinline__ float frelu(float v) { return v > 0.f ? v : 0.f; }

__device__ __forceinline__ short f2bf(float f) {
    unsigned u = __float_as_uint(f);
    unsigned r = (u + 0x7fffu + ((u >> 16) & 1u)) >> 16;
    return (short)r;
}
__device__ __forceinline__ float bf2f(short s) {
    return __uint_as_float(((unsigned)(unsigned short)s) << 16);
}

// ================= MEGA: rank (atomic pass) || prep (weights+input cvt+pooled zero) =================
__device__ __forceinline__ void tbf_one(const float* __restrict__ W, short* __restrict__ WT,
                                        int K, int Ncols, int KP, int idx) {
    int c = idx / KP, k = idx % KP;
    WT[(size_t)c * KP + k] = (k < K) ? f2bf(W[(size_t)k * Ncols + c]) : (short)0;
}

constexpr int RANK_B = Ee / 256;                 // 3125
constexpr int PREP_ELEMS = 20480 + 36864 + 36864 + 32768 + 8192 + 400000 + 16384;
constexpr int PREP_B = (PREP_ELEMS + 255) / 256; // 2155

__global__ void k_mega(const int* __restrict__ ei, int* __restrict__ degi,
                       int* __restrict__ rank,
                       const float* __restrict__ W0, const float* __restrict__ W1,
                       const float* __restrict__ W2, const float* __restrict__ fc1w,
                       const float* __restrict__ fc2w, const float* __restrict__ x_in,
                       short* __restrict__ WT0, short* __restrict__ WT1,
                       short* __restrict__ WT2, short* __restrict__ fc1wT,
                       short* __restrict__ fc2wT, short* __restrict__ xb0,
                       float* __restrict__ pooled) {
    int b = blockIdx.x;
    if (b < RANK_B) {
        int e = b * 256 + threadIdx.x;
        rank[e] = atomicAdd(&degi[ei[Ee + e]], 1);
        return;
    }
    int idx = (b - RANK_B) * 256 + threadIdx.x;
    if (idx < 20480) { tbf_one(W0, WT0, 144, 128, 160, idx); return; }
    idx -= 20480;
    if (idx < 36864) { tbf_one(W1, WT1, 272, 128, 288, idx); return; }
    idx -= 36864;
    if (idx < 36864) { tbf_one(W2, WT2, 272, 128, 288, idx); return; }
    idx -= 36864;
    if (idx < 32768) { tbf_one(fc1w, fc1wT, 128, 256, 128, idx); return; }
    idx -= 32768;
    if (idx < 8192) { tbf_one(fc2w, fc2wT, 256, 32, 256, idx); return; }
    idx -= 8192;
    if (idx < 400000) {
        float4 a = *(const float4*)(x_in + (size_t)idx * 8);
        float4 bq = *(const float4*)(x_in + (size_t)idx * 8 + 4);
        short8 h;
        h[0] = f2bf(a.x); h[1] = f2bf(a.y); h[2] = f2bf(a.z); h[3] = f2bf(a.w);
        h[4] = f2bf(bq.x); h[5] = f2bf(bq.y); h[6] = f2bf(bq.z); h[7] = f2bf(bq.w);
        *(short8*)(xb0 + (size_t)idx * 8) = h;
        return;
    }
    idx -= 400000;
    if (idx < 16384)
        *(float4*)(pooled + (size_t)idx * 4) = make_float4(0.f, 0.f, 0.f, 0.f);
}

// ================= scans =================
__global__ void k_scan_block(const int* __restrict__ in, int* __restrict__ out,
                             int* __restrict__ partials, int n) {
    __shared__ int s[256];
    int i = blockIdx.x * 256 + threadIdx.x;
    int v = (i < n) ? in[i] : 0;
    s[threadIdx.x] = v;
    __syncthreads();
    #pragma unroll
    for (int off = 1; off < 256; off <<= 1) {
        int t = (threadIdx.x >= off) ? s[threadIdx.x - off] : 0;
        __syncthreads();
        s[threadIdx.x] += t;
        __syncthreads();
    }
    if (i < n) out[i] = s[threadIdx.x] - v;
    if (threadIdx.x == 255) partials[blockIdx.x] = s[255];
}

// each block redundantly scans the 196 partials in LDS, then adds its prefix
constexpr int NB = (Nn + 255) / 256;   // 196
__global__ void k_scan_fin(int* __restrict__ rowptr, const int* __restrict__ partials) {
    __shared__ int s[256];
    int t = threadIdx.x;
    s[t] = (t < NB) ? partials[t] : 0;
    __syncthreads();
    #pragma unroll
    for (int off = 1; off < 256; off <<= 1) {
        int v = (t >= off) ? s[t - off] : 0;
        __syncthreads();
        s[t] += v;
        __syncthreads();
    }
    int add = (blockIdx.x == 0) ? 0 : s[blockIdx.x - 1];
    int i = blockIdx.x * 256 + t;
    if (i < Nn) rowptr[i] += add;
    if (i == 0) rowptr[Nn] = Ee;
}

// atomic-free bucket placement: both src-node and edge-id arrays
__global__ void k_fill2(const int* __restrict__ ei, const int* __restrict__ rowptr,
                        const int* __restrict__ rank, int* __restrict__ csr_src,
                        int* __restrict__ csr_eid) {
    int e = blockIdx.x * 256 + threadIdx.x;
    if (e >= Ee) return;
    int d = ei[Ee + e];
    int pos = rowptr[d] + rank[e];
    csr_src[pos] = ei[e];
    csr_eid[pos] = e;
}

// ================= wave-per-node gathers =================
// gather0 (CIN=64): 8 edge-slots x 8 chunks ; EA: 16 edge-slots x 4 chunks (f32)
constexpr int G0W_B = (Nn + 3) / 4;      // 12500 blocks (4 waves/block, 1 node/wave)
constexpr int EAW_B = (Nn + 3) / 4;      // 12500

__global__ __launch_bounds__(256) void k_g0ea(
    const int* __restrict__ rowptr, const int* __restrict__ csr_src,
    const int* __restrict__ csr_eid, const short* __restrict__ xb,
    const float* __restrict__ ea, short* __restrict__ G,
    short* __restrict__ eab)
{
    const int lane = threadIdx.x & 63;
    if (blockIdx.x < G0W_B) {
        // ---- feature gather CIN=64: wave per node ----
        int n = blockIdx.x * 4 + (threadIdx.x >> 6);
        if (n >= Nn) return;
        const int chunk = lane & 7;          // 8 chunks x 8 bf16
        const int eslot = lane >> 3;         // 8 slots
        int beg = rowptr[n], end = rowptr[n + 1];
        float acc[8] = {0.f, 0.f, 0.f, 0.f, 0.f, 0.f, 0.f, 0.f};
        int p = beg + eslot;
        for (; p + 8 < end; p += 16) {
            int s0 = csr_src[p], s1 = csr_src[p + 8];
            short8 v0 = *(const short8*)(xb + (size_t)s0 * INC + chunk * 8);
            short8 v1 = *(const short8*)(xb + (size_t)s1 * INC + chunk * 8);
            #pragma unroll
            for (int i = 0; i < 8; ++i) acc[i] += bf2f(v0[i]) + bf2f(v1[i]);
        }
        for (; p < end; p += 8) {
            int s0 = csr_src[p];
            short8 v0 = *(const short8*)(xb + (size_t)s0 * INC + chunk * 8);
            #pragma unroll
            for (int i = 0; i < 8; ++i) acc[i] += bf2f(v0[i]);
        }
        if (eslot == 0) {
            short8 xv = *(const short8*)(xb + (size_t)n * INC + chunk * 8);
            #pragma unroll
            for (int i = 0; i < 8; ++i) acc[i] += bf2f(xv[i]);
        }
        #pragma unroll
        for (int i = 0; i < 8; ++i) {
            acc[i] += __shfl_xor(acc[i], 8);
            acc[i] += __shfl_xor(acc[i], 16);
            acc[i] += __shfl_xor(acc[i], 32);
        }
        if (eslot == 0) {
            short8 h;
            #pragma unroll
            for (int i = 0; i < 8; ++i) h[i] = f2bf(acc[i]);
            *(short8*)(G + (size_t)n * INC + chunk * 8) = h;
        }
        return;
    }
    // ---- EA gather: wave per node, 16 slots x 4 f32-chunks ----
    int n = (blockIdx.x - G0W_B) * 4 + (threadIdx.x >> 6);
    if (n >= Nn) return;
    const int chunk = lane & 3;
    const int eslot = lane >> 2;             // 16 slots
    int beg = rowptr[n], end = rowptr[n + 1];
    float4 a = (eslot == 0) ? make_float4(1.f, 1.f, 1.f, 1.f)
                            : make_float4(0.f, 0.f, 0.f, 0.f);
    int p = beg + eslot;
    for (; p + 16 < end; p += 32) {
        int e0 = csr_eid[p], e1 = csr_eid[p + 16];
        float4 v0 = *(const float4*)(ea + (size_t)e0 * ECc + chunk * 4);
        float4 v1 = *(const float4*)(ea + (size_t)e1 * ECc + chunk * 4);
        a.x += v0.x + v1.x; a.y += v0.y + v1.y;
        a.z += v0.z + v1.z; a.w += v0.w + v1.w;
    }
    for (; p < end; p += 16) {
        int e0 = csr_eid[p];
        float4 v0 = *(const float4*)(ea + (size_t)e0 * ECc + chunk * 4);
        a.x += v0.x; a.y += v0.y; a.z += v0.z; a.w += v0.w;
    }
    #pragma unroll
    for (int m = 4; m <= 32; m <<= 1) {
        a.x += __shfl_xor(a.x, m); a.y += __shfl_xor(a.y, m);
        a.z += __shfl_xor(a.z, m); a.w += __shfl_xor(a.w, m);
    }
    if (eslot == 0) {
        short4v h;
        h[0] = f2bf(a.x); h[1] = f2bf(a.y); h[2] = f2bf(a.z); h[3] = f2bf(a.w);
        *(short4v*)(eab + (size_t)n * 32 + chunk * 4) = h;
        short4v z; z[0] = 0; z[1] = 0; z[2] = 0; z[3] = 0;
        *(short4v*)(eab + (size_t)n * 32 + 16 + chunk * 4) = z;
    }
}

// HC gather: wave per node, 4 edge-slots x 16 chunks
__global__ __launch_bounds__(256) void k_gather(
    const int* __restrict__ rowptr, const int* __restrict__ csr_src,
    const short* __restrict__ xb, short* __restrict__ G)
{
    int n = blockIdx.x * 4 + (threadIdx.x >> 6);
    if (n >= Nn) return;
    const int lane = threadIdx.x & 63;
    const int chunk = lane & 15;             // 16 chunks x 8 bf16
    const int eslot = lane >> 4;             // 4 slots
    int beg = rowptr[n], end = rowptr[n + 1];
    float acc[8] = {0.f, 0.f, 0.f, 0.f, 0.f, 0.f, 0.f, 0.f};
    int p = beg + eslot;
    for (; p + 4 < end; p += 8) {
        int s0 = csr_src[p], s1 = csr_src[p + 4];
        short8 v0 = *(const short8*)(xb + (size_t)s0 * HC + chunk * 8);
        short8 v1 = *(const short8*)(xb + (size_t)s1 * HC + chunk * 8);
        #pragma unroll
        for (int i = 0; i < 8; ++i) acc[i] += bf2f(v0[i]) + bf2f(v1[i]);
    }
    for (; p < end; p += 4) {
        int s0 = csr_src[p];
        short8 v0 = *(const short8*)(xb + (size_t)s0 * HC + chunk * 8);
        #pragma unroll
        for (int i = 0; i < 8; ++i) acc[i] += bf2f(v0[i]);
    }
    if (eslot == 0) {
        short8 xv = *(const short8*)(xb + (size_t)n * HC + chunk * 8);
        #pragma unroll
        for (int i = 0; i < 8; ++i) acc[i] += bf2f(xv[i]);
    }
    #pragma unroll
    for (int i = 0; i < 8; ++i) {
        acc[i] += __shfl_xor(acc[i], 16);
        acc[i] += __shfl_xor(acc[i], 32);
    }
    if (eslot == 0) {
        short8 h;
        #pragma unroll
        for (int i = 0; i < 8; ++i) h[i] = f2bf(acc[i]);
        *(short8*)(G + (size_t)n * HC + chunk * 8) = h;
    }
}

// ================= split-GEMM layer: acc = deg.(x@Ws) + G@Wn + EA@We; BN/relu =================
template<int CIN>
__global__ __launch_bounds__(256) void k_layer_mfma(
    const short* __restrict__ xs, const short* __restrict__ G,
    const short* __restrict__ eab, const short* __restrict__ WT,
    const int* __restrict__ degi, const float* __restrict__ bias,
    const float* __restrict__ gamma, const float* __restrict__ beta,
    const float* __restrict__ rmean, const float* __restrict__ rvar,
    short* __restrict__ xoutb)
{
    constexpr int KP = 2 * CIN + 32;
    const int wv = threadIdx.x >> 6, lane = threadIdx.x & 63;
    const int lr = lane & 15, lk = lane >> 4;
    const int row0 = blockIdx.x * 128 + wv * 32;
    const short* Xp0 = xs + (size_t)(row0 + lr) * CIN + lk * 8;
    const short* Xp1 = Xp0 + (size_t)16 * CIN;
    const short* Gp0 = G + (size_t)(row0 + lr) * CIN + lk * 8;
    const short* Gp1 = Gp0 + (size_t)16 * CIN;
    const short* Bp  = WT + (size_t)lr * KP + lk * 8;

    f32x4 acc[2][8];
    #pragma unroll
    for (int i = 0; i < 2; ++i)
        #pragma unroll
        for (int j = 0; j < 8; ++j) acc[i][j] = (f32x4){0.f, 0.f, 0.f, 0.f};

    // phase 1: self  x @ Wself  (WT k in [0,CIN))
    #pragma unroll
    for (int k0 = 0; k0 < CIN; k0 += 32) {
        short8 a0 = *(const short8*)(Xp0 + k0);
        short8 a1 = *(const short8*)(Xp1 + k0);
        #pragma unroll
        for (int j = 0; j < 8; ++j) {
            short8 b = *(const short8*)(Bp + (size_t)j * 16 * KP + k0);
            acc[0][j] = __builtin_amdgcn_mfma_f32_16x16x32_bf16(a0, b, acc[0][j], 0, 0, 0);
            acc[1][j] = __builtin_amdgcn_mfma_f32_16x16x32_bf16(a1, b, acc[1][j], 0, 0, 0);
        }
    }
    // per-row deg scale (exact: deg*(x@W) == (deg*x)@W)
    float dgs[2][4];
    #pragma unroll
    for (int rf = 0; rf < 2; ++rf) {
        int rbase = row0 + rf * 16 + lk * 4;
        #pragma unroll
        for (int i = 0; i < 4; ++i)
            dgs[rf][i] = (rbase + i < Nn) ? (float)(degi[rbase + i] + 1) : 0.f;
    }
    #pragma unroll
    for (int rf = 0; rf < 2; ++rf)
        #pragma unroll
        for (int j = 0; j < 8; ++j)
            #pragma unroll
            for (int i = 0; i < 4; ++i) acc[rf][j][i] *= dgs[rf][i];

    // phase 2: neighbor  G @ Wnbr  (WT k in [CIN,2CIN))
    #pragma unroll
    for (int k0 = 0; k0 < CIN; k0 += 32) {
        short8 a0 = *(const short8*)(Gp0 + k0);
        short8 a1 = *(const short8*)(Gp1 + k0);
        #pragma unroll
        for (int j = 0; j < 8; ++j) {
            short8 b = *(const short8*)(Bp + (size_t)j * 16 * KP + CIN + k0);
            acc[0][j] = __builtin_amdgcn_mfma_f32_16x16x32_bf16(a0, b, acc[0][j], 0, 0, 0);
            acc[1][j] = __builtin_amdgcn_mfma_f32_16x16x32_bf16(a1, b, acc[1][j], 0, 0, 0);
        }
    }
    // phase 3: EA @ Wea  (WT k in [2CIN, 2CIN+32), eab row = [EA|zeros])
    {
        short8 e0 = *(const short8*)(eab + (size_t)(row0 + lr) * 32 + lk * 8);
        short8 e1 = *(const short8*)(eab + (size_t)(row0 + 16 + lr) * 32 + lk * 8);
        #pragma unroll
        for (int j = 0; j < 8; ++j) {
            short8 b = *(const short8*)(Bp + (size_t)j * 16 * KP + 2 * CIN);
            acc[0][j] = __builtin_amdgcn_mfma_f32_16x16x32_bf16(e0, b, acc[0][j], 0, 0, 0);
            acc[1][j] = __builtin_amdgcn_mfma_f32_16x16x32_bf16(e1, b, acc[1][j], 0, 0, 0);
        }
    }

    #pragma unroll
    for (int rf = 0; rf < 2; ++rf) {
        int rbase = row0 + rf * 16 + lk * 4;
        #pragma unroll
        for (int j = 0; j < 8; ++j) {
            int c = j * 16 + lr;
            float bb = bias[c], gm = gamma[c], bt = beta[c], rm = rmean[c];
            float inv = rsqrtf(rvar[c] + 1e-5f);
            #pragma unroll
            for (int i = 0; i < 4; ++i) {
                int r = rbase + i;
                if (r < Nn) {
                    float v = frelu(acc[rf][j][i] + dgs[rf][i] * bb);
                    v = frelu((v - rm) * inv * gm + bt);
                    xoutb[(size_t)r * HC + c] = f2bf(v);
                }
            }
        }
    }
}

// ================= pooling (bf16 x, run-segmented) =================
__global__ void k_pool2(const short* __restrict__ xbf, const int* __restrict__ batch,
                        float* __restrict__ pooled) {
    constexpr int NPG = 64;
    int gid  = (blockIdx.x * 256 + threadIdx.x) >> 5;
    int lane = threadIdx.x & 31;
    int n0 = gid * NPG;
    if (n0 >= Nn) return;
    int nend = min(n0 + NPG, Nn);
    int curg = batch[n0];
    float4 acc = make_float4(0.f, 0.f, 0.f, 0.f);
    for (int n = n0; n < nend; ++n) {
        int g = batch[n];
        if (g != curg) {
            float* p = pooled + (size_t)curg * HC + lane * 4;
            atomicAdd(p + 0, acc.x); atomicAdd(p + 1, acc.y);
            atomicAdd(p + 2, acc.z); atomicAdd(p + 3, acc.w);
            acc = make_float4(0.f, 0.f, 0.f, 0.f);
            curg = g;
        }
        short4v v = *(const short4v*)(xbf + (size_t)n * HC + lane * 4);
        acc.x += bf2f(v[0]); acc.y += bf2f(v[1]);
        acc.z += bf2f(v[2]); acc.w += bf2f(v[3]);
    }
    float* p = pooled + (size_t)curg * HC + lane * 4;
    atomicAdd(p + 0, acc.x); atomicAdd(p + 1, acc.y);
    atomicAdd(p + 2, acc.z); atomicAdd(p + 3, acc.w);
}

// ================= Prow = pooled @ fc1_w[128:,:] + fc1_b -> bf16 =================
__global__ void k_prow(const float* __restrict__ pooled, const float* __restrict__ fc1w,
                       const float* __restrict__ fc1b, short* __restrict__ prowb) {
    int g = blockIdx.x;
    int j = threadIdx.x;
    __shared__ float ps[HC];
    if (j < HC) ps[j] = pooled[(size_t)g * HC + j];
    __syncthreads();
    float v = fc1b[j];
    #pragma unroll 4
    for (int k = 0; k < HC; ++k)
        v += ps[k] * fc1w[(size_t)(HC + k) * MLPc + j];
    prowb[(size_t)g * MLPc + j] = f2bf(v);
}

// ================= fused fc1+fc2 (MFMA, 8 waves, vectorized prow pass) =================
__global__ __launch_bounds__(512) void k_fc_mfma(
    const short* __restrict__ xbf, const short* __restrict__ prowb,
    const int* __restrict__ batch, const short* __restrict__ fc1wT,  // [256][128]
    const short* __restrict__ fc2wT,                                  // [32][256]
    const float* __restrict__ fc2b, float* __restrict__ out)
{
    __shared__ short8 ldsv[4096];           // 64 KB
    char* lds = (char*)ldsv;
    const int tid = threadIdx.x;
    const int wv = tid >> 6, lane = tid & 63;
    const int lr = lane & 15, lk = lane >> 4;
    const int row0 = blockIdx.x * 128;

    const short* Ap = xbf + (size_t)(row0 + wv * 16 + lr) * HC + lk * 8;
    short8 a0 = *(const short8*)(Ap + 0);
    short8 a1 = *(const short8*)(Ap + 32);
    short8 a2 = *(const short8*)(Ap + 64);
    short8 a3 = *(const short8*)(Ap + 96);

    #pragma unroll
    for (int i = 0; i < 8; ++i) {
        int elem = tid + i * 512;
        int row  = elem >> 4;
        int colb = (elem & 15) << 4;
        short8 v = *(const short8*)(fc1wT + (size_t)elem * 8);
        *(short8*)(lds + row * 256 + (colb ^ ((row & 15) << 4))) = v;
    }
    __syncthreads();

    f32x4 acc[16];
    #pragma unroll
    for (int j = 0; j < 16; ++j) acc[j] = (f32x4){0.f, 0.f, 0.f, 0.f};
    short8 av[4] = {a0, a1, a2, a3};
    #pragma unroll
    for (int k = 0; k < 4; ++k) {
        int o = (k * 32 + lk * 8) * 2;
        #pragma unroll
        for (int j = 0; j < 16; ++j) {
            int brow = j * 16 + lr;
            short8 b = *(const short8*)(lds + brow * 256 + (o ^ ((brow & 15) << 4)));
            acc[j] = __builtin_amdgcn_mfma_f32_16x16x32_bf16(av[k], b, acc[j], 0, 0, 0);
        }
    }
    __syncthreads();

    const int rl0 = wv * 16 + lk * 4;
    #pragma unroll
    for (int j = 0; j < 16; ++j) {
        int c = j * 16 + lr;
        #pragma unroll
        for (int i = 0; i < 4; ++i) {
            int rl = rl0 + i;
            *(short*)(lds + rl * 512 + ((c * 2) ^ ((rl & 15) << 4))) = f2bf(acc[j][i]);
        }
    }
    __syncthreads();

    {
        int rl = tid >> 2, qq = tid & 3;
        int r = row0 + rl;
        if (r < Nn) {
            int g = batch[r];
            const short* pr = prowb + (size_t)g * MLPc + qq * 64;
            int sw = (rl & 15) << 4;
            char* hrow = lds + rl * 512;
            #pragma unroll
            for (int jj = 0; jj < 8; ++jj) {
                int c0 = qq * 64 + jj * 8;
                short8 pv = *(const short8*)(pr + jj * 8);
                short8 hv = *(const short8*)(hrow + ((c0 * 2) ^ sw));
                short8 ho;
                #pragma unroll
                for (int u = 0; u < 8; ++u)
                    ho[u] = f2bf(frelu(bf2f(hv[u]) + bf2f(pv[u])));
                *(short8*)(hrow + ((c0 * 2) ^ sw)) = ho;
            }
        }
    }
    __syncthreads();

    f32x4 acc2[2];
    acc2[0] = (f32x4){0.f, 0.f, 0.f, 0.f};
    acc2[1] = (f32x4){0.f, 0.f, 0.f, 0.f};
    const int r0l = wv * 16 + lr;
    const char* hrow = lds + r0l * 512;
    const int sw0 = (r0l & 15) << 4;
    #pragma unroll
    for (int k0 = 0; k0 < 256; k0 += 32) {
        int o = (k0 + lk * 8) * 2;
        short8 a = *(const short8*)(hrow + (o ^ sw0));
        #pragma unroll
        for (int cf = 0; cf < 2; ++cf) {
            short8 b = *(const short8*)(fc2wT + (size_t)(cf * 16 + lr) * 256 + k0 + lk * 8);
            acc2[cf] = __builtin_amdgcn_mfma_f32_16x16x32_bf16(a, b, acc2[cf], 0, 0, 0);
        }
    }
    const int rbase = row0 + wv * 16 + lk * 4;
    #pragma unroll
    for (int cf = 0; cf < 2; ++cf) {
        int c = cf * 16 + lr;
        float bb = fc2b[c];
        #pragma unroll
        for (int i = 0; i < 4; ++i) {
            int r = rbase + i;
            if (r < Nn) out[(size_t)r * NCc + c] = acc2[cf][i] + bb;
        }
    }
}

// ================= launch =================
extern "C" void kernel_launch(void* const* d_in, const int* in_sizes, int n_in,
                              void* d_out, int out_size, void* d_ws, size_t ws_size,
                              hipStream_t stream) {
    const float* x_in  = (const float*)d_in[0];
    const int*   ei    = (const int*)d_in[1];
    const float* ea    = (const float*)d_in[2];
    const int*   batch = (const int*)d_in[3];
    const float* W0 = (const float*)d_in[4];
    const float* b0 = (const float*)d_in[5];
    const float* g0 = (const float*)d_in[6];
    const float* be0 = (const float*)d_in[7];
    const float* rm0 = (const float*)d_in[8];
    const float* rv0 = (const float*)d_in[9];
    const float* W1 = (const float*)d_in[10];
    const float* b1 = (const float*)d_in[11];
    const float* g1 = (const float*)d_in[12];
    const float* be1 = (const float*)d_in[13];
    const float* rm1 = (const float*)d_in[14];
    const float* rv1 = (const float*)d_in[15];
    const float* W2 = (const float*)d_in[16];
    const float* b2 = (const float*)d_in[17];
    const float* g2 = (const float*)d_in[18];
    const float* be2 = (const float*)d_in[19];
    const float* rm2 = (const float*)d_in[20];
    const float* rv2 = (const float*)d_in[21];
    const float* fc1w = (const float*)d_in[22];
    const float* fc1b = (const float*)d_in[23];
    const float* fc2w = (const float*)d_in[24];
    const float* fc2b = (const float*)d_in[25];

    size_t off = 0;
    auto alloc = [&](size_t bytes) {
        void* p = (char*)d_ws + off;
        off += (bytes + 255) & ~(size_t)255;
        return p;
    };
    int*   rowptr   = (int*)alloc((size_t)(Nn + 1) * 4);
    int*   partials = (int*)alloc(256 * 4);
    int*   rank     = (int*)alloc((size_t)Ee * 4);
    int*   degi     = (int*)alloc((size_t)Nn * 4);
    short* eab      = (short*)alloc((size_t)Mpad * 32 * 2);
    short* xb0      = (short*)alloc((size_t)Mpad * INC * 2);
    short* xbA      = (short*)alloc((size_t)Mpad * HC * 2);
    short* xb3      = (short*)alloc((size_t)Mpad * HC * 2);
    short* G        = (short*)alloc((size_t)Mpad * HC * 2);
    short* WT0      = (short*)alloc((size_t)HC * 160 * 2);
    short* WT1      = (short*)alloc((size_t)HC * 288 * 2);
    short* WT2      = (short*)alloc((size_t)HC * 288 * 2);
    short* fc1wT    = (short*)alloc((size_t)MLPc * 128 * 2);
    short* fc2wT    = (short*)alloc((size_t)NCc * 256 * 2);
    float* pooled   = (float*)alloc((size_t)Gg * HC * 4);
    short* prowb    = (short*)alloc((size_t)Gg * MLPc * 2);

    // csr arrays live in d_out (6.4 MB = exactly 2x 3.2 MB); dead before k_fc writes out
    int* csr_src = (int*)d_out;
    int* csr_eid = csr_src + Ee;

    // ---- CSR build: rank co-runs with prep ----
    hipMemsetAsync(degi, 0, (size_t)Nn * 4, stream);
    k_mega<<<RANK_B + PREP_B, 256, 0, stream>>>(ei, degi, rank,
        W0, W1, W2, fc1w, fc2w, x_in, WT0, WT1, WT2, fc1wT, fc2wT, xb0, pooled);
    k_scan_block<<<NB, 256, 0, stream>>>(degi, rowptr, partials, Nn);
    k_scan_fin<<<NB, 256, 0, stream>>>(rowptr, partials);
    k_fill2<<<(Ee + 255) / 256, 256, 0, stream>>>(ei, rowptr, rank, csr_src, csr_eid);

    const int LGRID = (Mpad + 127) / 128;   // 391

    // ---- layer 0: gather (+EA) then GEMM ----
    k_g0ea<<<G0W_B + EAW_B, 256, 0, stream>>>(rowptr, csr_src, csr_eid, xb0, ea, G, eab);
    k_layer_mfma<INC><<<LGRID, 256, 0, stream>>>(xb0, G, eab, WT0, degi,
        b0, g0, be0, rm0, rv0, xbA);

    // ---- layer 1 (in-place: layer reads only its own rows of xbA) ----
    k_gather<<<(Nn + 3) / 4, 256, 0, stream>>>(rowptr, csr_src, xbA, G);
    k_layer_mfma<HC><<<LGRID, 256, 0, stream>>>(xbA, G, eab, WT1, degi,
        b1, g1, be1, rm1, rv1, xbA);

    // ---- layer 2 ----
    k_gather<<<(Nn + 3) / 4, 256, 0, stream>>>(rowptr, csr_src, xbA, G);
    k_layer_mfma<HC><<<LGRID, 256, 0, stream>>>(xbA, G, eab, WT2, degi,
        b2, g2, be2, rm2, rv2, xb3);

    // ---- pool + Prow (pooled pre-zeroed in k_mega) ----
    k_pool2<<<((Nn + 63) / 64 * 32 + 255) / 256, 256, 0, stream>>>(xb3, batch, pooled);
    k_prow<<<Gg, 256, 0, stream>>>(pooled, fc1w, fc1b, prowb);

    // ---- fused fc1 + fc2 ----
    k_fc_mfma<<<(Mpad + 127) / 128, 512, 0, stream>>>(xb3, prowb, batch, fc1wT, fc2wT,
                                                      fc2b, (float*)d_out);
}

// Round 11
// 301.793 us; speedup vs baseline: 1.0203x; 1.0203x over previous
//
#include <hip/hip_runtime.h>

constexpr int Nn   = 50000;
constexpr int Ee   = 800000;
constexpr int INC  = 64;
constexpr int HC   = 128;
constexpr int ECc  = 16;
constexpr int MLPc = 256;
constexpr int NCc  = 32;
constexpr int Gg   = 512;
constexpr int Mpad = 50048;          // 391*128

typedef __attribute__((ext_vector_type(8))) short short8;
typedef __attribute__((ext_vector_type(4))) short short4v;
typedef __attribute__((ext_vector_type(4))) float f32x4;

__device__ __forceinline__ float frelu(float v) { return v > 0.f ? v : 0.f; }

__device__ __forceinline__ short f2bf(float f) {
    unsigned u = __float_as_uint(f);
    unsigned r = (u + 0x7fffu + ((u >> 16) & 1u)) >> 16;
    return (short)r;
}
__device__ __forceinline__ float bf2f(short s) {
    return __uint_as_float(((unsigned)(unsigned short)s) << 16);
}

// ================= MEGA: rank (atomic pass) || prep (weights+x+ea cvt+pooled zero) =================
__device__ __forceinline__ void tbf_one(const float* __restrict__ W, short* __restrict__ WT,
                                        int K, int Ncols, int KP, int idx) {
    int c = idx / KP, k = idx % KP;
    WT[(size_t)c * KP + k] = (k < K) ? f2bf(W[(size_t)k * Ncols + c]) : (short)0;
}

constexpr int RANK_B = Ee / 256;                 // 3125
constexpr int EACVT  = Ee * ECc / 8;             // 1,600,000
constexpr int PREP_ELEMS = 20480 + 36864 + 36864 + 32768 + 8192 + 400000 + 16384 + EACVT;
constexpr int PREP_B = (PREP_ELEMS + 255) / 256;

__global__ void k_mega(const int* __restrict__ ei, int* __restrict__ degi,
                       int* __restrict__ rank,
                       const float* __restrict__ W0, const float* __restrict__ W1,
                       const float* __restrict__ W2, const float* __restrict__ fc1w,
                       const float* __restrict__ fc2w, const float* __restrict__ x_in,
                       const float* __restrict__ ea,
                       short* __restrict__ WT0, short* __restrict__ WT1,
                       short* __restrict__ WT2, short* __restrict__ fc1wT,
                       short* __restrict__ fc2wT, short* __restrict__ xb0,
                       short* __restrict__ eabf, float* __restrict__ pooled) {
    int b = blockIdx.x;
    if (b < RANK_B) {
        int e = b * 256 + threadIdx.x;
        rank[e] = atomicAdd(&degi[ei[Ee + e]], 1);
        return;
    }
    int idx = (b - RANK_B) * 256 + threadIdx.x;
    if (idx < 20480) { tbf_one(W0, WT0, 144, 128, 160, idx); return; }
    idx -= 20480;
    if (idx < 36864) { tbf_one(W1, WT1, 272, 128, 288, idx); return; }
    idx -= 36864;
    if (idx < 36864) { tbf_one(W2, WT2, 272, 128, 288, idx); return; }
    idx -= 36864;
    if (idx < 32768) { tbf_one(fc1w, fc1wT, 128, 256, 128, idx); return; }
    idx -= 32768;
    if (idx < 8192) { tbf_one(fc2w, fc2wT, 256, 32, 256, idx); return; }
    idx -= 8192;
    if (idx < 400000) {
        float4 a = *(const float4*)(x_in + (size_t)idx * 8);
        float4 bq = *(const float4*)(x_in + (size_t)idx * 8 + 4);
        short8 h;
        h[0] = f2bf(a.x); h[1] = f2bf(a.y); h[2] = f2bf(a.z); h[3] = f2bf(a.w);
        h[4] = f2bf(bq.x); h[5] = f2bf(bq.y); h[6] = f2bf(bq.z); h[7] = f2bf(bq.w);
        *(short8*)(xb0 + (size_t)idx * 8) = h;
        return;
    }
    idx -= 400000;
    if (idx < 16384) {
        *(float4*)(pooled + (size_t)idx * 4) = make_float4(0.f, 0.f, 0.f, 0.f);
        return;
    }
    idx -= 16384;
    if (idx < EACVT) {
        float4 a = *(const float4*)(ea + (size_t)idx * 8);
        float4 bq = *(const float4*)(ea + (size_t)idx * 8 + 4);
        short8 h;
        h[0] = f2bf(a.x); h[1] = f2bf(a.y); h[2] = f2bf(a.z); h[3] = f2bf(a.w);
        h[4] = f2bf(bq.x); h[5] = f2bf(bq.y); h[6] = f2bf(bq.z); h[7] = f2bf(bq.w);
        *(short8*)(eabf + (size_t)idx * 8) = h;
    }
}

// ================= scans =================
__global__ void k_scan_block(const int* __restrict__ in, int* __restrict__ out,
                             int* __restrict__ partials, int n) {
    __shared__ int s[256];
    int i = blockIdx.x * 256 + threadIdx.x;
    int v = (i < n) ? in[i] : 0;
    s[threadIdx.x] = v;
    __syncthreads();
    #pragma unroll
    for (int off = 1; off < 256; off <<= 1) {
        int t = (threadIdx.x >= off) ? s[threadIdx.x - off] : 0;
        __syncthreads();
        s[threadIdx.x] += t;
        __syncthreads();
    }
    if (i < n) out[i] = s[threadIdx.x] - v;
    if (threadIdx.x == 255) partials[blockIdx.x] = s[255];
}

constexpr int NB = (Nn + 255) / 256;   // 196
__global__ void k_scan_fin(int* __restrict__ rowptr, const int* __restrict__ partials) {
    __shared__ int s[256];
    int t = threadIdx.x;
    s[t] = (t < NB) ? partials[t] : 0;
    __syncthreads();
    #pragma unroll
    for (int off = 1; off < 256; off <<= 1) {
        int v = (t >= off) ? s[t - off] : 0;
        __syncthreads();
        s[t] += v;
        __syncthreads();
    }
    int add = (blockIdx.x == 0) ? 0 : s[blockIdx.x - 1];
    int i = blockIdx.x * 256 + t;
    if (i < Nn) rowptr[i] += add;
    if (i == 0) rowptr[Nn] = Ee;
}

// atomic-free bucket placement: both src-node and edge-id arrays
__global__ void k_fill2(const int* __restrict__ ei, const int* __restrict__ rowptr,
                        const int* __restrict__ rank, int* __restrict__ csr_src,
                        int* __restrict__ csr_eid) {
    int e = blockIdx.x * 256 + threadIdx.x;
    if (e >= Ee) return;
    int d = ei[Ee + e];
    int pos = rowptr[d] + rank[e];
    csr_src[pos] = ei[e];
    csr_eid[pos] = e;
}

// ================= gather0 || EA gather (thread-per-chunk, 4-unroll) =================
constexpr int G0_B = (Nn * (INC / 8) + 255) / 256;   // 1563
constexpr int EA_B = (Nn * 2 + 255) / 256;           // 391

__global__ __launch_bounds__(256) void k_g0ea(
    const int* __restrict__ rowptr, const int* __restrict__ csr_src,
    const int* __restrict__ csr_eid, const short* __restrict__ xb,
    const short* __restrict__ eabf, short* __restrict__ G,
    short* __restrict__ eab)
{
    int b = blockIdx.x;
    if (b < G0_B) {
        // feature gather, CIN=64: 8 threads/node
        int idx = b * 256 + threadIdx.x;
        int n = idx >> 3, q = idx & 7;
        if (n >= Nn) return;
        int beg = rowptr[n], end = rowptr[n + 1];
        float acc[8] = {0.f, 0.f, 0.f, 0.f, 0.f, 0.f, 0.f, 0.f};
        int p = beg;
        for (; p + 3 < end; p += 4) {
            int s0 = csr_src[p], s1 = csr_src[p + 1];
            int s2 = csr_src[p + 2], s3 = csr_src[p + 3];
            short8 v0 = *(const short8*)(xb + (size_t)s0 * INC + q * 8);
            short8 v1 = *(const short8*)(xb + (size_t)s1 * INC + q * 8);
            short8 v2 = *(const short8*)(xb + (size_t)s2 * INC + q * 8);
            short8 v3 = *(const short8*)(xb + (size_t)s3 * INC + q * 8);
            #pragma unroll
            for (int i = 0; i < 8; ++i)
                acc[i] += (bf2f(v0[i]) + bf2f(v1[i])) + (bf2f(v2[i]) + bf2f(v3[i]));
        }
        for (; p < end; ++p) {
            int s0 = csr_src[p];
            short8 v0 = *(const short8*)(xb + (size_t)s0 * INC + q * 8);
            #pragma unroll
            for (int i = 0; i < 8; ++i) acc[i] += bf2f(v0[i]);
        }
        short8 xv = *(const short8*)(xb + (size_t)n * INC + q * 8);
        short8 h;
        #pragma unroll
        for (int i = 0; i < 8; ++i) h[i] = f2bf(acc[i] + bf2f(xv[i]));
        *(short8*)(G + (size_t)n * INC + q * 8) = h;
        return;
    }
    // EA gather (bf16 ea): 2 threads/node, 8-elem chunks
    int idx = (b - G0_B) * 256 + threadIdx.x;
    int n = idx >> 1, q = idx & 1;
    if (n >= Nn) return;
    float acc[8] = {1.f, 1.f, 1.f, 1.f, 1.f, 1.f, 1.f, 1.f};   // self-loop fill
    int beg = rowptr[n], end = rowptr[n + 1];
    int p = beg;
    for (; p + 3 < end; p += 4) {
        int e0 = csr_eid[p], e1 = csr_eid[p + 1];
        int e2 = csr_eid[p + 2], e3 = csr_eid[p + 3];
        short8 v0 = *(const short8*)(eabf + (size_t)e0 * ECc + q * 8);
        short8 v1 = *(const short8*)(eabf + (size_t)e1 * ECc + q * 8);
        short8 v2 = *(const short8*)(eabf + (size_t)e2 * ECc + q * 8);
        short8 v3 = *(const short8*)(eabf + (size_t)e3 * ECc + q * 8);
        #pragma unroll
        for (int i = 0; i < 8; ++i)
            acc[i] += (bf2f(v0[i]) + bf2f(v1[i])) + (bf2f(v2[i]) + bf2f(v3[i]));
    }
    for (; p < end; ++p) {
        int e0 = csr_eid[p];
        short8 v0 = *(const short8*)(eabf + (size_t)e0 * ECc + q * 8);
        #pragma unroll
        for (int i = 0; i < 8; ++i) acc[i] += bf2f(v0[i]);
    }
    short8 h;
    #pragma unroll
    for (int i = 0; i < 8; ++i) h[i] = f2bf(acc[i]);
    *(short8*)(eab + (size_t)n * 32 + q * 8) = h;
    short8 z = (short8){0, 0, 0, 0, 0, 0, 0, 0};
    *(short8*)(eab + (size_t)n * 32 + 16 + q * 8) = z;
}

// ================= neighbor gather (HC): 16 threads/node, 4-unroll =================
__global__ __launch_bounds__(256) void k_gather(
    const int* __restrict__ rowptr, const int* __restrict__ csr_src,
    const short* __restrict__ xb, short* __restrict__ G)
{
    constexpr int TPN = HC / 8;
    int idx = blockIdx.x * 256 + threadIdx.x;
    int n = idx / TPN, q = idx % TPN;
    if (n >= Nn) return;
    int beg = rowptr[n], end = rowptr[n + 1];
    float acc[8] = {0.f, 0.f, 0.f, 0.f, 0.f, 0.f, 0.f, 0.f};
    int p = beg;
    for (; p + 3 < end; p += 4) {
        int s0 = csr_src[p], s1 = csr_src[p + 1];
        int s2 = csr_src[p + 2], s3 = csr_src[p + 3];
        short8 v0 = *(const short8*)(xb + (size_t)s0 * HC + q * 8);
        short8 v1 = *(const short8*)(xb + (size_t)s1 * HC + q * 8);
        short8 v2 = *(const short8*)(xb + (size_t)s2 * HC + q * 8);
        short8 v3 = *(const short8*)(xb + (size_t)s3 * HC + q * 8);
        #pragma unroll
        for (int i = 0; i < 8; ++i)
            acc[i] += (bf2f(v0[i]) + bf2f(v1[i])) + (bf2f(v2[i]) + bf2f(v3[i]));
    }
    for (; p < end; ++p) {
        int s0 = csr_src[p];
        short8 v0 = *(const short8*)(xb + (size_t)s0 * HC + q * 8);
        #pragma unroll
        for (int i = 0; i < 8; ++i) acc[i] += bf2f(v0[i]);
    }
    short8 xv = *(const short8*)(xb + (size_t)n * HC + q * 8);
    short8 h;
    #pragma unroll
    for (int i = 0; i < 8; ++i) h[i] = f2bf(acc[i] + bf2f(xv[i]));
    *(short8*)(G + (size_t)n * HC + q * 8) = h;
}

// ================= split-GEMM layer: acc = deg.(x@Ws) + G@Wn + EA@We; BN/relu =================
template<int CIN>
__global__ __launch_bounds__(256) void k_layer_mfma(
    const short* __restrict__ xs, const short* __restrict__ G,
    const short* __restrict__ eab, const short* __restrict__ WT,
    const int* __restrict__ degi, const float* __restrict__ bias,
    const float* __restrict__ gamma, const float* __restrict__ beta,
    const float* __restrict__ rmean, const float* __restrict__ rvar,
    short* __restrict__ xoutb)
{
    constexpr int KP = 2 * CIN + 32;
    const int wv = threadIdx.x >> 6, lane = threadIdx.x & 63;
    const int lr = lane & 15, lk = lane >> 4;
    const int row0 = blockIdx.x * 128 + wv * 32;
    const short* Xp0 = xs + (size_t)(row0 + lr) * CIN + lk * 8;
    const short* Xp1 = Xp0 + (size_t)16 * CIN;
    const short* Gp0 = G + (size_t)(row0 + lr) * CIN + lk * 8;
    const short* Gp1 = Gp0 + (size_t)16 * CIN;
    const short* Bp  = WT + (size_t)lr * KP + lk * 8;

    f32x4 acc[2][8];
    #pragma unroll
    for (int i = 0; i < 2; ++i)
        #pragma unroll
        for (int j = 0; j < 8; ++j) acc[i][j] = (f32x4){0.f, 0.f, 0.f, 0.f};

    #pragma unroll
    for (int k0 = 0; k0 < CIN; k0 += 32) {
        short8 a0 = *(const short8*)(Xp0 + k0);
        short8 a1 = *(const short8*)(Xp1 + k0);
        #pragma unroll
        for (int j = 0; j < 8; ++j) {
            short8 b = *(const short8*)(Bp + (size_t)j * 16 * KP + k0);
            acc[0][j] = __builtin_amdgcn_mfma_f32_16x16x32_bf16(a0, b, acc[0][j], 0, 0, 0);
            acc[1][j] = __builtin_amdgcn_mfma_f32_16x16x32_bf16(a1, b, acc[1][j], 0, 0, 0);
        }
    }
    float dgs[2][4];
    #pragma unroll
    for (int rf = 0; rf < 2; ++rf) {
        int rbase = row0 + rf * 16 + lk * 4;
        #pragma unroll
        for (int i = 0; i < 4; ++i)
            dgs[rf][i] = (rbase + i < Nn) ? (float)(degi[rbase + i] + 1) : 0.f;
    }
    #pragma unroll
    for (int rf = 0; rf < 2; ++rf)
        #pragma unroll
        for (int j = 0; j < 8; ++j)
            #pragma unroll
            for (int i = 0; i < 4; ++i) acc[rf][j][i] *= dgs[rf][i];

    #pragma unroll
    for (int k0 = 0; k0 < CIN; k0 += 32) {
        short8 a0 = *(const short8*)(Gp0 + k0);
        short8 a1 = *(const short8*)(Gp1 + k0);
        #pragma unroll
        for (int j = 0; j < 8; ++j) {
            short8 b = *(const short8*)(Bp + (size_t)j * 16 * KP + CIN + k0);
            acc[0][j] = __builtin_amdgcn_mfma_f32_16x16x32_bf16(a0, b, acc[0][j], 0, 0, 0);
            acc[1][j] = __builtin_amdgcn_mfma_f32_16x16x32_bf16(a1, b, acc[1][j], 0, 0, 0);
        }
    }
    {
        short8 e0 = *(const short8*)(eab + (size_t)(row0 + lr) * 32 + lk * 8);
        short8 e1 = *(const short8*)(eab + (size_t)(row0 + 16 + lr) * 32 + lk * 8);
        #pragma unroll
        for (int j = 0; j < 8; ++j) {
            short8 b = *(const short8*)(Bp + (size_t)j * 16 * KP + 2 * CIN);
            acc[0][j] = __builtin_amdgcn_mfma_f32_16x16x32_bf16(e0, b, acc[0][j], 0, 0, 0);
            acc[1][j] = __builtin_amdgcn_mfma_f32_16x16x32_bf16(e1, b, acc[1][j], 0, 0, 0);
        }
    }

    #pragma unroll
    for (int rf = 0; rf < 2; ++rf) {
        int rbase = row0 + rf * 16 + lk * 4;
        #pragma unroll
        for (int j = 0; j < 8; ++j) {
            int c = j * 16 + lr;
            float bb = bias[c], gm = gamma[c], bt = beta[c], rm = rmean[c];
            float inv = rsqrtf(rvar[c] + 1e-5f);
            #pragma unroll
            for (int i = 0; i < 4; ++i) {
                int r = rbase + i;
                if (r < Nn) {
                    float v = frelu(acc[rf][j][i] + dgs[rf][i] * bb);
                    v = frelu((v - rm) * inv * gm + bt);
                    xoutb[(size_t)r * HC + c] = f2bf(v);
                }
            }
        }
    }
}

// ================= pooling (bf16 x, run-segmented) =================
__global__ void k_pool2(const short* __restrict__ xbf, const int* __restrict__ batch,
                        float* __restrict__ pooled) {
    constexpr int NPG = 64;
    int gid  = (blockIdx.x * 256 + threadIdx.x) >> 5;
    int lane = threadIdx.x & 31;
    int n0 = gid * NPG;
    if (n0 >= Nn) return;
    int nend = min(n0 + NPG, Nn);
    int curg = batch[n0];
    float4 acc = make_float4(0.f, 0.f, 0.f, 0.f);
    for (int n = n0; n < nend; ++n) {
        int g = batch[n];
        if (g != curg) {
            float* p = pooled + (size_t)curg * HC + lane * 4;
            atomicAdd(p + 0, acc.x); atomicAdd(p + 1, acc.y);
            atomicAdd(p + 2, acc.z); atomicAdd(p + 3, acc.w);
            acc = make_float4(0.f, 0.f, 0.f, 0.f);
            curg = g;
        }
        short4v v = *(const short4v*)(xbf + (size_t)n * HC + lane * 4);
        acc.x += bf2f(v[0]); acc.y += bf2f(v[1]);
        acc.z += bf2f(v[2]); acc.w += bf2f(v[3]);
    }
    float* p = pooled + (size_t)curg * HC + lane * 4;
    atomicAdd(p + 0, acc.x); atomicAdd(p + 1, acc.y);
    atomicAdd(p + 2, acc.z); atomicAdd(p + 3, acc.w);
}

// ================= Prow = pooled @ fc1_w[128:,:] + fc1_b -> bf16 =================
__global__ void k_prow(const float* __restrict__ pooled, const float* __restrict__ fc1w,
                       const float* __restrict__ fc1b, short* __restrict__ prowb) {
    int g = blockIdx.x;
    int j = threadIdx.x;
    __shared__ float ps[HC];
    if (j < HC) ps[j] = pooled[(size_t)g * HC + j];
    __syncthreads();
    float v = fc1b[j];
    #pragma unroll 4
    for (int k = 0; k < HC; ++k)
        v += ps[k] * fc1w[(size_t)(HC + k) * MLPc + j];
    prowb[(size_t)g * MLPc + j] = f2bf(v);
}

// ================= fused fc1+fc2 (MFMA, 8 waves, vectorized prow pass) =================
__global__ __launch_bounds__(512) void k_fc_mfma(
    const short* __restrict__ xbf, const short* __restrict__ prowb,
    const int* __restrict__ batch, const short* __restrict__ fc1wT,  // [256][128]
    const short* __restrict__ fc2wT,                                  // [32][256]
    const float* __restrict__ fc2b, float* __restrict__ out)
{
    __shared__ short8 ldsv[4096];           // 64 KB
    char* lds = (char*)ldsv;
    const int tid = threadIdx.x;
    const int wv = tid >> 6, lane = tid & 63;
    const int lr = lane & 15, lk = lane >> 4;
    const int row0 = blockIdx.x * 128;

    const short* Ap = xbf + (size_t)(row0 + wv * 16 + lr) * HC + lk * 8;
    short8 a0 = *(const short8*)(Ap + 0);
    short8 a1 = *(const short8*)(Ap + 32);
    short8 a2 = *(const short8*)(Ap + 64);
    short8 a3 = *(const short8*)(Ap + 96);

    #pragma unroll
    for (int i = 0; i < 8; ++i) {
        int elem = tid + i * 512;
        int row  = elem >> 4;
        int colb = (elem & 15) << 4;
        short8 v = *(const short8*)(fc1wT + (size_t)elem * 8);
        *(short8*)(lds + row * 256 + (colb ^ ((row & 15) << 4))) = v;
    }
    __syncthreads();

    f32x4 acc[16];
    #pragma unroll
    for (int j = 0; j < 16; ++j) acc[j] = (f32x4){0.f, 0.f, 0.f, 0.f};
    short8 av[4] = {a0, a1, a2, a3};
    #pragma unroll
    for (int k = 0; k < 4; ++k) {
        int o = (k * 32 + lk * 8) * 2;
        #pragma unroll
        for (int j = 0; j < 16; ++j) {
            int brow = j * 16 + lr;
            short8 b = *(const short8*)(lds + brow * 256 + (o ^ ((brow & 15) << 4)));
            acc[j] = __builtin_amdgcn_mfma_f32_16x16x32_bf16(av[k], b, acc[j], 0, 0, 0);
        }
    }
    __syncthreads();

    const int rl0 = wv * 16 + lk * 4;
    #pragma unroll
    for (int j = 0; j < 16; ++j) {
        int c = j * 16 + lr;
        #pragma unroll
        for (int i = 0; i < 4; ++i) {
            int rl = rl0 + i;
            *(short*)(lds + rl * 512 + ((c * 2) ^ ((rl & 15) << 4))) = f2bf(acc[j][i]);
        }
    }
    __syncthreads();

    {
        int rl = tid >> 2, qq = tid & 3;
        int r = row0 + rl;
        if (r < Nn) {
            int g = batch[r];
            const short* pr = prowb + (size_t)g * MLPc + qq * 64;
            int sw = (rl & 15) << 4;
            char* hrow = lds + rl * 512;
            #pragma unroll
            for (int jj = 0; jj < 8; ++jj) {
                int c0 = qq * 64 + jj * 8;
                short8 pv = *(const short8*)(pr + jj * 8);
                short8 hv = *(const short8*)(hrow + ((c0 * 2) ^ sw));
                short8 ho;
                #pragma unroll
                for (int u = 0; u < 8; ++u)
                    ho[u] = f2bf(frelu(bf2f(hv[u]) + bf2f(pv[u])));
                *(short8*)(hrow + ((c0 * 2) ^ sw)) = ho;
            }
        }
    }
    __syncthreads();

    f32x4 acc2[2];
    acc2[0] = (f32x4){0.f, 0.f, 0.f, 0.f};
    acc2[1] = (f32x4){0.f, 0.f, 0.f, 0.f};
    const int r0l = wv * 16 + lr;
    const char* hrow = lds + r0l * 512;
    const int sw0 = (r0l & 15) << 4;
    #pragma unroll
    for (int k0 = 0; k0 < 256; k0 += 32) {
        int o = (k0 + lk * 8) * 2;
        short8 a = *(const short8*)(hrow + (o ^ sw0));
        #pragma unroll
        for (int cf = 0; cf < 2; ++cf) {
            short8 b = *(const short8*)(fc2wT + (size_t)(cf * 16 + lr) * 256 + k0 + lk * 8);
            acc2[cf] = __builtin_amdgcn_mfma_f32_16x16x32_bf16(a, b, acc2[cf], 0, 0, 0);
        }
    }
    const int rbase = row0 + wv * 16 + lk * 4;
    #pragma unroll
    for (int cf = 0; cf < 2; ++cf) {
        int c = cf * 16 + lr;
        float bb = fc2b[c];
        #pragma unroll
        for (int i = 0; i < 4; ++i) {
            int r = rbase + i;
            if (r < Nn) out[(size_t)r * NCc + c] = acc2[cf][i] + bb;
        }
    }
}

// ================= launch =================
extern "C" void kernel_launch(void* const* d_in, const int* in_sizes, int n_in,
                              void* d_out, int out_size, void* d_ws, size_t ws_size,
                              hipStream_t stream) {
    const float* x_in  = (const float*)d_in[0];
    const int*   ei    = (const int*)d_in[1];
    const float* ea    = (const float*)d_in[2];
    const int*   batch = (const int*)d_in[3];
    const float* W0 = (const float*)d_in[4];
    const float* b0 = (const float*)d_in[5];
    const float* g0 = (const float*)d_in[6];
    const float* be0 = (const float*)d_in[7];
    const float* rm0 = (const float*)d_in[8];
    const float* rv0 = (const float*)d_in[9];
    const float* W1 = (const float*)d_in[10];
    const float* b1 = (const float*)d_in[11];
    const float* g1 = (const float*)d_in[12];
    const float* be1 = (const float*)d_in[13];
    const float* rm1 = (const float*)d_in[14];
    const float* rv1 = (const float*)d_in[15];
    const float* W2 = (const float*)d_in[16];
    const float* b2 = (const float*)d_in[17];
    const float* g2 = (const float*)d_in[18];
    const float* be2 = (const float*)d_in[19];
    const float* rm2 = (const float*)d_in[20];
    const float* rv2 = (const float*)d_in[21];
    const float* fc1w = (const float*)d_in[22];
    const float* fc1b = (const float*)d_in[23];
    const float* fc2w = (const float*)d_in[24];
    const float* fc2b = (const float*)d_in[25];

    size_t off = 0;
    auto alloc = [&](size_t bytes) {
        void* p = (char*)d_ws + off;
        off += (bytes + 255) & ~(size_t)255;
        return p;
    };
    int*   rowptr   = (int*)alloc((size_t)(Nn + 1) * 4);
    int*   partials = (int*)alloc(256 * 4);
    int*   rank     = (int*)alloc((size_t)Ee * 4);
    int*   degi     = (int*)alloc((size_t)Nn * 4);
    short* eabf     = (short*)alloc((size_t)Ee * ECc * 2);
    short* eab      = (short*)alloc((size_t)Mpad * 32 * 2);
    short* xb0      = (short*)alloc((size_t)Mpad * INC * 2);
    short* xbA      = (short*)alloc((size_t)Mpad * HC * 2);
    short* xb3      = (short*)alloc((size_t)Mpad * HC * 2);
    short* G        = (short*)alloc((size_t)Mpad * HC * 2);
    short* WT0      = (short*)alloc((size_t)HC * 160 * 2);
    short* WT1      = (short*)alloc((size_t)HC * 288 * 2);
    short* WT2      = (short*)alloc((size_t)HC * 288 * 2);
    short* fc1wT    = (short*)alloc((size_t)MLPc * 128 * 2);
    short* fc2wT    = (short*)alloc((size_t)NCc * 256 * 2);
    float* pooled   = (float*)alloc((size_t)Gg * HC * 4);
    short* prowb    = (short*)alloc((size_t)Gg * MLPc * 2);

    // csr arrays live in d_out (6.4 MB = exactly 2x 3.2 MB); dead before k_fc writes out
    int* csr_src = (int*)d_out;
    int* csr_eid = csr_src + Ee;

    // ---- CSR build: rank co-runs with prep ----
    hipMemsetAsync(degi, 0, (size_t)Nn * 4, stream);
    k_mega<<<RANK_B + PREP_B, 256, 0, stream>>>(ei, degi, rank,
        W0, W1, W2, fc1w, fc2w, x_in, ea,
        WT0, WT1, WT2, fc1wT, fc2wT, xb0, eabf, pooled);
    k_scan_block<<<NB, 256, 0, stream>>>(degi, rowptr, partials, Nn);
    k_scan_fin<<<NB, 256, 0, stream>>>(rowptr, partials);
    k_fill2<<<(Ee + 255) / 256, 256, 0, stream>>>(ei, rowptr, rank, csr_src, csr_eid);

    const int LGRID = (Mpad + 127) / 128;   // 391

    // ---- layer 0: gather (+EA) then GEMM ----
    k_g0ea<<<G0_B + EA_B, 256, 0, stream>>>(rowptr, csr_src, csr_eid, xb0, eabf, G, eab);
    k_layer_mfma<INC><<<LGRID, 256, 0, stream>>>(xb0, G, eab, WT0, degi,
        b0, g0, be0, rm0, rv0, xbA);

    // ---- layer 1 (in-place: layer reads only its own rows of xbA) ----
    k_gather<<<(Nn * (HC / 8) + 255) / 256, 256, 0, stream>>>(rowptr, csr_src, xbA, G);
    k_layer_mfma<HC><<<LGRID, 256, 0, stream>>>(xbA, G, eab, WT1, degi,
        b1, g1, be1, rm1, rv1, xbA);

    // ---- layer 2 ----
    k_gather<<<(Nn * (HC / 8) + 255) / 256, 256, 0, stream>>>(rowptr, csr_src, xbA, G);
    k_layer_mfma<HC><<<LGRID, 256, 0, stream>>>(xbA, G, eab, WT2, degi,
        b2, g2, be2, rm2, rv2, xb3);

    // ---- pool + Prow (pooled pre-zeroed in k_mega) ----
    k_pool2<<<((Nn + 63) / 64 * 32 + 255) / 256, 256, 0, stream>>>(xb3, batch, pooled);
    k_prow<<<Gg, 256, 0, stream>>>(pooled, fc1w, fc1b, prowb);

    // ---- fused fc1 + fc2 ----
    k_fc_mfma<<<(Mpad + 127) / 128, 512, 0, stream>>>(xb3, prowb, batch, fc1wT, fc2wT,
                                                      fc2b, (float*)d_out);
}

// Round 12
// 286.855 us; speedup vs baseline: 1.0735x; 1.0521x over previous
//
#include <hip/hip_runtime.h>

constexpr int Nn   = 50000;
constexpr int Ee   = 800000;
constexpr int INC  = 64;
constexpr int HC   = 128;
constexpr int ECc  = 16;
constexpr int MLPc = 256;
constexpr int NCc  = 32;
constexpr int Gg   = 512;
constexpr int Mpad = 50048;          // 391*128

typedef __attribute__((ext_vector_type(8))) short short8;
typedef __attribute__((ext_vector_type(4))) short short4v;
typedef __attribute__((ext_vector_type(4))) float f32x4;

__device__ __forceinline__ float frelu(float v) { return v > 0.f ? v : 0.f; }

__device__ __forceinline__ short f2bf(float f) {
    unsigned u = __float_as_uint(f);
    unsigned r = (u + 0x7fffu + ((u >> 16) & 1u)) >> 16;
    return (short)r;
}
__device__ __forceinline__ float bf2f(short s) {
    return __uint_as_float(((unsigned)(unsigned short)s) << 16);
}

// ================= MEGA: rank (4 edges/thread, MLP) || prep (weights+x cvt+pooled zero) =================
__device__ __forceinline__ void tbf_one(const float* __restrict__ W, short* __restrict__ WT,
                                        int K, int Ncols, int KP, int idx) {
    int c = idx / KP, k = idx % KP;
    WT[(size_t)c * KP + k] = (k < K) ? f2bf(W[(size_t)k * Ncols + c]) : (short)0;
}

constexpr int RANK_B = (Ee + 1023) / 1024;       // 782 (4 edges/thread)
constexpr int PREP_ELEMS = 20480 + 36864 + 36864 + 32768 + 8192 + 400000 + 16384;
constexpr int PREP_B = (PREP_ELEMS + 255) / 256; // 2155

__global__ void k_mega(const int* __restrict__ ei, int* __restrict__ degi,
                       int* __restrict__ rank,
                       const float* __restrict__ W0, const float* __restrict__ W1,
                       const float* __restrict__ W2, const float* __restrict__ fc1w,
                       const float* __restrict__ fc2w, const float* __restrict__ x_in,
                       short* __restrict__ WT0, short* __restrict__ WT1,
                       short* __restrict__ WT2, short* __restrict__ fc1wT,
                       short* __restrict__ fc2wT, short* __restrict__ xb0,
                       float* __restrict__ pooled) {
    int b = blockIdx.x;
    if (b < RANK_B) {
        int e0 = b * 1024 + threadIdx.x;
        int e1 = e0 + 256, e2 = e0 + 512, e3 = e0 + 768;
        // 4 independent return-atomics in flight per thread
        int r0, r1, r2, r3;
        if (e0 < Ee) r0 = atomicAdd(&degi[ei[Ee + e0]], 1);
        if (e1 < Ee) r1 = atomicAdd(&degi[ei[Ee + e1]], 1);
        if (e2 < Ee) r2 = atomicAdd(&degi[ei[Ee + e2]], 1);
        if (e3 < Ee) r3 = atomicAdd(&degi[ei[Ee + e3]], 1);
        if (e0 < Ee) rank[e0] = r0;
        if (e1 < Ee) rank[e1] = r1;
        if (e2 < Ee) rank[e2] = r2;
        if (e3 < Ee) rank[e3] = r3;
        return;
    }
    int idx = (b - RANK_B) * 256 + threadIdx.x;
    if (idx < 20480) { tbf_one(W0, WT0, 144, 128, 160, idx); return; }
    idx -= 20480;
    if (idx < 36864) { tbf_one(W1, WT1, 272, 128, 288, idx); return; }
    idx -= 36864;
    if (idx < 36864) { tbf_one(W2, WT2, 272, 128, 288, idx); return; }
    idx -= 36864;
    if (idx < 32768) { tbf_one(fc1w, fc1wT, 128, 256, 128, idx); return; }
    idx -= 32768;
    if (idx < 8192) { tbf_one(fc2w, fc2wT, 256, 32, 256, idx); return; }
    idx -= 8192;
    if (idx < 400000) {
        float4 a = *(const float4*)(x_in + (size_t)idx * 8);
        float4 bq = *(const float4*)(x_in + (size_t)idx * 8 + 4);
        short8 h;
        h[0] = f2bf(a.x); h[1] = f2bf(a.y); h[2] = f2bf(a.z); h[3] = f2bf(a.w);
        h[4] = f2bf(bq.x); h[5] = f2bf(bq.y); h[6] = f2bf(bq.z); h[7] = f2bf(bq.w);
        *(short8*)(xb0 + (size_t)idx * 8) = h;
        return;
    }
    idx -= 400000;
    if (idx < 16384)
        *(float4*)(pooled + (size_t)idx * 4) = make_float4(0.f, 0.f, 0.f, 0.f);
}

// ================= scans =================
__global__ void k_scan_block(const int* __restrict__ in, int* __restrict__ out,
                             int* __restrict__ partials, int n) {
    __shared__ int s[256];
    int i = blockIdx.x * 256 + threadIdx.x;
    int v = (i < n) ? in[i] : 0;
    s[threadIdx.x] = v;
    __syncthreads();
    #pragma unroll
    for (int off = 1; off < 256; off <<= 1) {
        int t = (threadIdx.x >= off) ? s[threadIdx.x - off] : 0;
        __syncthreads();
        s[threadIdx.x] += t;
        __syncthreads();
    }
    if (i < n) out[i] = s[threadIdx.x] - v;
    if (threadIdx.x == 255) partials[blockIdx.x] = s[255];
}

constexpr int NB = (Nn + 255) / 256;   // 196
__global__ void k_scan_fin(int* __restrict__ rowptr, const int* __restrict__ partials) {
    __shared__ int s[256];
    int t = threadIdx.x;
    s[t] = (t < NB) ? partials[t] : 0;
    __syncthreads();
    #pragma unroll
    for (int off = 1; off < 256; off <<= 1) {
        int v = (t >= off) ? s[t - off] : 0;
        __syncthreads();
        s[t] += v;
        __syncthreads();
    }
    int add = (blockIdx.x == 0) ? 0 : s[blockIdx.x - 1];
    int i = blockIdx.x * 256 + t;
    if (i < Nn) rowptr[i] += add;
    if (i == 0) rowptr[Nn] = Ee;
}

// ================= bucket placement + EA pre-scatter (bf16, CSR order) =================
__global__ void k_fill3(const int* __restrict__ ei, const int* __restrict__ rowptr,
                        const int* __restrict__ rank, const float* __restrict__ ea,
                        int* __restrict__ csr_src, short* __restrict__ eacsr) {
    int e = blockIdx.x * 256 + threadIdx.x;
    if (e >= Ee) return;
    int d = ei[Ee + e];
    int pos = rowptr[d] + rank[e];
    csr_src[pos] = ei[e];
    const float* src = ea + (size_t)e * ECc;
    float4 a0 = *(const float4*)(src);
    float4 a1 = *(const float4*)(src + 4);
    float4 a2 = *(const float4*)(src + 8);
    float4 a3 = *(const float4*)(src + 12);
    short8 h0, h1;
    h0[0] = f2bf(a0.x); h0[1] = f2bf(a0.y); h0[2] = f2bf(a0.z); h0[3] = f2bf(a0.w);
    h0[4] = f2bf(a1.x); h0[5] = f2bf(a1.y); h0[6] = f2bf(a1.z); h0[7] = f2bf(a1.w);
    h1[0] = f2bf(a2.x); h1[1] = f2bf(a2.y); h1[2] = f2bf(a2.z); h1[3] = f2bf(a2.w);
    h1[4] = f2bf(a3.x); h1[5] = f2bf(a3.y); h1[6] = f2bf(a3.z); h1[7] = f2bf(a3.w);
    short* dst = eacsr + (size_t)pos * ECc;
    *(short8*)dst = h0;
    *(short8*)(dst + 8) = h1;
}

// ================= gather0 || EA reduce (contiguous) =================
constexpr int G0_B = (Nn * (INC / 8) + 255) / 256;   // 1563
constexpr int EA_B = (Nn * 2 + 255) / 256;           // 391

__global__ __launch_bounds__(256) void k_g0ea(
    const int* __restrict__ rowptr, const int* __restrict__ csr_src,
    const short* __restrict__ xb, const short* __restrict__ eacsr,
    short* __restrict__ G, short* __restrict__ eab)
{
    int b = blockIdx.x;
    if (b < G0_B) {
        // feature gather, CIN=64: 8 threads/node, 4-unroll
        int idx = b * 256 + threadIdx.x;
        int n = idx >> 3, q = idx & 7;
        if (n >= Nn) return;
        int beg = rowptr[n], end = rowptr[n + 1];
        float acc[8] = {0.f, 0.f, 0.f, 0.f, 0.f, 0.f, 0.f, 0.f};
        int p = beg;
        for (; p + 3 < end; p += 4) {
            int s0 = csr_src[p], s1 = csr_src[p + 1];
            int s2 = csr_src[p + 2], s3 = csr_src[p + 3];
            short8 v0 = *(const short8*)(xb + (size_t)s0 * INC + q * 8);
            short8 v1 = *(const short8*)(xb + (size_t)s1 * INC + q * 8);
            short8 v2 = *(const short8*)(xb + (size_t)s2 * INC + q * 8);
            short8 v3 = *(const short8*)(xb + (size_t)s3 * INC + q * 8);
            #pragma unroll
            for (int i = 0; i < 8; ++i)
                acc[i] += (bf2f(v0[i]) + bf2f(v1[i])) + (bf2f(v2[i]) + bf2f(v3[i]));
        }
        for (; p < end; ++p) {
            int s0 = csr_src[p];
            short8 v0 = *(const short8*)(xb + (size_t)s0 * INC + q * 8);
            #pragma unroll
            for (int i = 0; i < 8; ++i) acc[i] += bf2f(v0[i]);
        }
        short8 xv = *(const short8*)(xb + (size_t)n * INC + q * 8);
        short8 h;
        #pragma unroll
        for (int i = 0; i < 8; ++i) h[i] = f2bf(acc[i] + bf2f(xv[i]));
        *(short8*)(G + (size_t)n * INC + q * 8) = h;
        return;
    }
    // EA reduce: contiguous eacsr rows, 2 threads/node
    int idx = (b - G0_B) * 256 + threadIdx.x;
    int n = idx >> 1, q = idx & 1;
    if (n >= Nn) return;
    float acc[8] = {1.f, 1.f, 1.f, 1.f, 1.f, 1.f, 1.f, 1.f};   // self-loop fill
    int beg = rowptr[n], end = rowptr[n + 1];
    int p = beg;
    for (; p + 1 < end; p += 2) {
        short8 v0 = *(const short8*)(eacsr + (size_t)p * ECc + q * 8);
        short8 v1 = *(const short8*)(eacsr + (size_t)(p + 1) * ECc + q * 8);
        #pragma unroll
        for (int i = 0; i < 8; ++i) acc[i] += bf2f(v0[i]) + bf2f(v1[i]);
    }
    if (p < end) {
        short8 v0 = *(const short8*)(eacsr + (size_t)p * ECc + q * 8);
        #pragma unroll
        for (int i = 0; i < 8; ++i) acc[i] += bf2f(v0[i]);
    }
    short8 h;
    #pragma unroll
    for (int i = 0; i < 8; ++i) h[i] = f2bf(acc[i]);
    *(short8*)(eab + (size_t)n * 32 + q * 8) = h;
    short8 z = (short8){0, 0, 0, 0, 0, 0, 0, 0};
    *(short8*)(eab + (size_t)n * 32 + 16 + q * 8) = z;
}

// ================= neighbor gather (HC): 16 threads/node, 4-unroll =================
__global__ __launch_bounds__(256) void k_gather(
    const int* __restrict__ rowptr, const int* __restrict__ csr_src,
    const short* __restrict__ xb, short* __restrict__ G)
{
    constexpr int TPN = HC / 8;
    int idx = blockIdx.x * 256 + threadIdx.x;
    int n = idx / TPN, q = idx % TPN;
    if (n >= Nn) return;
    int beg = rowptr[n], end = rowptr[n + 1];
    float acc[8] = {0.f, 0.f, 0.f, 0.f, 0.f, 0.f, 0.f, 0.f};
    int p = beg;
    for (; p + 3 < end; p += 4) {
        int s0 = csr_src[p], s1 = csr_src[p + 1];
        int s2 = csr_src[p + 2], s3 = csr_src[p + 3];
        short8 v0 = *(const short8*)(xb + (size_t)s0 * HC + q * 8);
        short8 v1 = *(const short8*)(xb + (size_t)s1 * HC + q * 8);
        short8 v2 = *(const short8*)(xb + (size_t)s2 * HC + q * 8);
        short8 v3 = *(const short8*)(xb + (size_t)s3 * HC + q * 8);
        #pragma unroll
        for (int i = 0; i < 8; ++i)
            acc[i] += (bf2f(v0[i]) + bf2f(v1[i])) + (bf2f(v2[i]) + bf2f(v3[i]));
    }
    for (; p < end; ++p) {
        int s0 = csr_src[p];
        short8 v0 = *(const short8*)(xb + (size_t)s0 * HC + q * 8);
        #pragma unroll
        for (int i = 0; i < 8; ++i) acc[i] += bf2f(v0[i]);
    }
    short8 xv = *(const short8*)(xb + (size_t)n * HC + q * 8);
    short8 h;
    #pragma unroll
    for (int i = 0; i < 8; ++i) h[i] = f2bf(acc[i] + bf2f(xv[i]));
    *(short8*)(G + (size_t)n * HC + q * 8) = h;
}

// ================= split-GEMM layer: acc = deg.(x@Ws) + G@Wn + EA@We; BN/relu =================
template<int CIN>
__global__ __launch_bounds__(256) void k_layer_mfma(
    const short* __restrict__ xs, const short* __restrict__ G,
    const short* __restrict__ eab, const short* __restrict__ WT,
    const int* __restrict__ degi, const float* __restrict__ bias,
    const float* __restrict__ gamma, const float* __restrict__ beta,
    const float* __restrict__ rmean, const float* __restrict__ rvar,
    short* __restrict__ xoutb)
{
    constexpr int KP = 2 * CIN + 32;
    const int wv = threadIdx.x >> 6, lane = threadIdx.x & 63;
    const int lr = lane & 15, lk = lane >> 4;
    const int row0 = blockIdx.x * 128 + wv * 32;
    const short* Xp0 = xs + (size_t)(row0 + lr) * CIN + lk * 8;
    const short* Xp1 = Xp0 + (size_t)16 * CIN;
    const short* Gp0 = G + (size_t)(row0 + lr) * CIN + lk * 8;
    const short* Gp1 = Gp0 + (size_t)16 * CIN;
    const short* Bp  = WT + (size_t)lr * KP + lk * 8;

    f32x4 acc[2][8];
    #pragma unroll
    for (int i = 0; i < 2; ++i)
        #pragma unroll
        for (int j = 0; j < 8; ++j) acc[i][j] = (f32x4){0.f, 0.f, 0.f, 0.f};

    #pragma unroll
    for (int k0 = 0; k0 < CIN; k0 += 32) {
        short8 a0 = *(const short8*)(Xp0 + k0);
        short8 a1 = *(const short8*)(Xp1 + k0);
        #pragma unroll
        for (int j = 0; j < 8; ++j) {
            short8 b = *(const short8*)(Bp + (size_t)j * 16 * KP + k0);
            acc[0][j] = __builtin_amdgcn_mfma_f32_16x16x32_bf16(a0, b, acc[0][j], 0, 0, 0);
            acc[1][j] = __builtin_amdgcn_mfma_f32_16x16x32_bf16(a1, b, acc[1][j], 0, 0, 0);
        }
    }
    float dgs[2][4];
    #pragma unroll
    for (int rf = 0; rf < 2; ++rf) {
        int rbase = row0 + rf * 16 + lk * 4;
        #pragma unroll
        for (int i = 0; i < 4; ++i)
            dgs[rf][i] = (rbase + i < Nn) ? (float)(degi[rbase + i] + 1) : 0.f;
    }
    #pragma unroll
    for (int rf = 0; rf < 2; ++rf)
        #pragma unroll
        for (int j = 0; j < 8; ++j)
            #pragma unroll
            for (int i = 0; i < 4; ++i) acc[rf][j][i] *= dgs[rf][i];

    #pragma unroll
    for (int k0 = 0; k0 < CIN; k0 += 32) {
        short8 a0 = *(const short8*)(Gp0 + k0);
        short8 a1 = *(const short8*)(Gp1 + k0);
        #pragma unroll
        for (int j = 0; j < 8; ++j) {
            short8 b = *(const short8*)(Bp + (size_t)j * 16 * KP + CIN + k0);
            acc[0][j] = __builtin_amdgcn_mfma_f32_16x16x32_bf16(a0, b, acc[0][j], 0, 0, 0);
            acc[1][j] = __builtin_amdgcn_mfma_f32_16x16x32_bf16(a1, b, acc[1][j], 0, 0, 0);
        }
    }
    {
        short8 e0 = *(const short8*)(eab + (size_t)(row0 + lr) * 32 + lk * 8);
        short8 e1 = *(const short8*)(eab + (size_t)(row0 + 16 + lr) * 32 + lk * 8);
        #pragma unroll
        for (int j = 0; j < 8; ++j) {
            short8 b = *(const short8*)(Bp + (size_t)j * 16 * KP + 2 * CIN);
            acc[0][j] = __builtin_amdgcn_mfma_f32_16x16x32_bf16(e0, b, acc[0][j], 0, 0, 0);
            acc[1][j] = __builtin_amdgcn_mfma_f32_16x16x32_bf16(e1, b, acc[1][j], 0, 0, 0);
        }
    }

    #pragma unroll
    for (int rf = 0; rf < 2; ++rf) {
        int rbase = row0 + rf * 16 + lk * 4;
        #pragma unroll
        for (int j = 0; j < 8; ++j) {
            int c = j * 16 + lr;
            float bb = bias[c], gm = gamma[c], bt = beta[c], rm = rmean[c];
            float inv = rsqrtf(rvar[c] + 1e-5f);
            #pragma unroll
            for (int i = 0; i < 4; ++i) {
                int r = rbase + i;
                if (r < Nn) {
                    float v = frelu(acc[rf][j][i] + dgs[rf][i] * bb);
                    v = frelu((v - rm) * inv * gm + bt);
                    xoutb[(size_t)r * HC + c] = f2bf(v);
                }
            }
        }
    }
}

// ================= pooling (bf16 x, run-segmented) =================
__global__ void k_pool2(const short* __restrict__ xbf, const int* __restrict__ batch,
                        float* __restrict__ pooled) {
    constexpr int NPG = 64;
    int gid  = (blockIdx.x * 256 + threadIdx.x) >> 5;
    int lane = threadIdx.x & 31;
    int n0 = gid * NPG;
    if (n0 >= Nn) return;
    int nend = min(n0 + NPG, Nn);
    int curg = batch[n0];
    float4 acc = make_float4(0.f, 0.f, 0.f, 0.f);
    for (int n = n0; n < nend; ++n) {
        int g = batch[n];
        if (g != curg) {
            float* p = pooled + (size_t)curg * HC + lane * 4;
            atomicAdd(p + 0, acc.x); atomicAdd(p + 1, acc.y);
            atomicAdd(p + 2, acc.z); atomicAdd(p + 3, acc.w);
            acc = make_float4(0.f, 0.f, 0.f, 0.f);
            curg = g;
        }
        short4v v = *(const short4v*)(xbf + (size_t)n * HC + lane * 4);
        acc.x += bf2f(v[0]); acc.y += bf2f(v[1]);
        acc.z += bf2f(v[2]); acc.w += bf2f(v[3]);
    }
    float* p = pooled + (size_t)curg * HC + lane * 4;
    atomicAdd(p + 0, acc.x); atomicAdd(p + 1, acc.y);
    atomicAdd(p + 2, acc.z); atomicAdd(p + 3, acc.w);
}

// ================= Prow = pooled @ fc1_w[128:,:] + fc1_b -> bf16 =================
__global__ void k_prow(const float* __restrict__ pooled, const float* __restrict__ fc1w,
                       const float* __restrict__ fc1b, short* __restrict__ prowb) {
    int g = blockIdx.x;
    int j = threadIdx.x;
    __shared__ float ps[HC];
    if (j < HC) ps[j] = pooled[(size_t)g * HC + j];
    __syncthreads();
    float v = fc1b[j];
    #pragma unroll 4
    for (int k = 0; k < HC; ++k)
        v += ps[k] * fc1w[(size_t)(HC + k) * MLPc + j];
    prowb[(size_t)g * MLPc + j] = f2bf(v);
}

// ================= fused fc1+fc2 (MFMA, 8 waves, vectorized prow pass) =================
__global__ __launch_bounds__(512) void k_fc_mfma(
    const short* __restrict__ xbf, const short* __restrict__ prowb,
    const int* __restrict__ batch, const short* __restrict__ fc1wT,  // [256][128]
    const short* __restrict__ fc2wT,                                  // [32][256]
    const float* __restrict__ fc2b, float* __restrict__ out)
{
    __shared__ short8 ldsv[4096];           // 64 KB
    char* lds = (char*)ldsv;
    const int tid = threadIdx.x;
    const int wv = tid >> 6, lane = tid & 63;
    const int lr = lane & 15, lk = lane >> 4;
    const int row0 = blockIdx.x * 128;

    const short* Ap = xbf + (size_t)(row0 + wv * 16 + lr) * HC + lk * 8;
    short8 a0 = *(const short8*)(Ap + 0);
    short8 a1 = *(const short8*)(Ap + 32);
    short8 a2 = *(const short8*)(Ap + 64);
    short8 a3 = *(const short8*)(Ap + 96);

    #pragma unroll
    for (int i = 0; i < 8; ++i) {
        int elem = tid + i * 512;
        int row  = elem >> 4;
        int colb = (elem & 15) << 4;
        short8 v = *(const short8*)(fc1wT + (size_t)elem * 8);
        *(short8*)(lds + row * 256 + (colb ^ ((row & 15) << 4))) = v;
    }
    __syncthreads();

    f32x4 acc[16];
    #pragma unroll
    for (int j = 0; j < 16; ++j) acc[j] = (f32x4){0.f, 0.f, 0.f, 0.f};
    short8 av[4] = {a0, a1, a2, a3};
    #pragma unroll
    for (int k = 0; k < 4; ++k) {
        int o = (k * 32 + lk * 8) * 2;
        #pragma unroll
        for (int j = 0; j < 16; ++j) {
            int brow = j * 16 + lr;
            short8 b = *(const short8*)(lds + brow * 256 + (o ^ ((brow & 15) << 4)));
            acc[j] = __builtin_amdgcn_mfma_f32_16x16x32_bf16(av[k], b, acc[j], 0, 0, 0);
        }
    }
    __syncthreads();

    const int rl0 = wv * 16 + lk * 4;
    #pragma unroll
    for (int j = 0; j < 16; ++j) {
        int c = j * 16 + lr;
        #pragma unroll
        for (int i = 0; i < 4; ++i) {
            int rl = rl0 + i;
            *(short*)(lds + rl * 512 + ((c * 2) ^ ((rl & 15) << 4))) = f2bf(acc[j][i]);
        }
    }
    __syncthreads();

    {
        int rl = tid >> 2, qq = tid & 3;
        int r = row0 + rl;
        if (r < Nn) {
            int g = batch[r];
            const short* pr = prowb + (size_t)g * MLPc + qq * 64;
            int sw = (rl & 15) << 4;
            char* hrow = lds + rl * 512;
            #pragma unroll
            for (int jj = 0; jj < 8; ++jj) {
                int c0 = qq * 64 + jj * 8;
                short8 pv = *(const short8*)(pr + jj * 8);
                short8 hv = *(const short8*)(hrow + ((c0 * 2) ^ sw));
                short8 ho;
                #pragma unroll
                for (int u = 0; u < 8; ++u)
                    ho[u] = f2bf(frelu(bf2f(hv[u]) + bf2f(pv[u])));
                *(short8*)(hrow + ((c0 * 2) ^ sw)) = ho;
            }
        }
    }
    __syncthreads();

    f32x4 acc2[2];
    acc2[0] = (f32x4){0.f, 0.f, 0.f, 0.f};
    acc2[1] = (f32x4){0.f, 0.f, 0.f, 0.f};
    const int r0l = wv * 16 + lr;
    const char* hrow = lds + r0l * 512;
    const int sw0 = (r0l & 15) << 4;
    #pragma unroll
    for (int k0 = 0; k0 < 256; k0 += 32) {
        int o = (k0 + lk * 8) * 2;
        short8 a = *(const short8*)(hrow + (o ^ sw0));
        #pragma unroll
        for (int cf = 0; cf < 2; ++cf) {
            short8 b = *(const short8*)(fc2wT + (size_t)(cf * 16 + lr) * 256 + k0 + lk * 8);
            acc2[cf] = __builtin_amdgcn_mfma_f32_16x16x32_bf16(a, b, acc2[cf], 0, 0, 0);
        }
    }
    const int rbase = row0 + wv * 16 + lk * 4;
    #pragma unroll
    for (int cf = 0; cf < 2; ++cf) {
        int c = cf * 16 + lr;
        float bb = fc2b[c];
        #pragma unroll
        for (int i = 0; i < 4; ++i) {
            int r = rbase + i;
            if (r < Nn) out[(size_t)r * NCc + c] = acc2[cf][i] + bb;
        }
    }
}

// ================= launch =================
extern "C" void kernel_launch(void* const* d_in, const int* in_sizes, int n_in,
                              void* d_out, int out_size, void* d_ws, size_t ws_size,
                              hipStream_t stream) {
    const float* x_in  = (const float*)d_in[0];
    const int*   ei    = (const int*)d_in[1];
    const float* ea    = (const float*)d_in[2];
    const int*   batch = (const int*)d_in[3];
    const float* W0 = (const float*)d_in[4];
    const float* b0 = (const float*)d_in[5];
    const float* g0 = (const float*)d_in[6];
    const float* be0 = (const float*)d_in[7];
    const float* rm0 = (const float*)d_in[8];
    const float* rv0 = (const float*)d_in[9];
    const float* W1 = (const float*)d_in[10];
    const float* b1 = (const float*)d_in[11];
    const float* g1 = (const float*)d_in[12];
    const float* be1 = (const float*)d_in[13];
    const float* rm1 = (const float*)d_in[14];
    const float* rv1 = (const float*)d_in[15];
    const float* W2 = (const float*)d_in[16];
    const float* b2 = (const float*)d_in[17];
    const float* g2 = (const float*)d_in[18];
    const float* be2 = (const float*)d_in[19];
    const float* rm2 = (const float*)d_in[20];
    const float* rv2 = (const float*)d_in[21];
    const float* fc1w = (const float*)d_in[22];
    const float* fc1b = (const float*)d_in[23];
    const float* fc2w = (const float*)d_in[24];
    const float* fc2b = (const float*)d_in[25];

    size_t off = 0;
    auto alloc = [&](size_t bytes) {
        void* p = (char*)d_ws + off;
        off += (bytes + 255) & ~(size_t)255;
        return p;
    };
    int*   rowptr   = (int*)alloc((size_t)(Nn + 1) * 4);
    int*   partials = (int*)alloc(256 * 4);
    int*   rank     = (int*)alloc((size_t)Ee * 4);
    int*   degi     = (int*)alloc((size_t)Nn * 4);
    short* eacsr    = (short*)alloc((size_t)Ee * ECc * 2);
    short* eab      = (short*)alloc((size_t)Mpad * 32 * 2);
    short* xb0      = (short*)alloc((size_t)Mpad * INC * 2);
    short* xbA      = (short*)alloc((size_t)Mpad * HC * 2);
    short* xb3      = (short*)alloc((size_t)Mpad * HC * 2);
    short* G        = (short*)alloc((size_t)Mpad * HC * 2);
    short* WT0      = (short*)alloc((size_t)HC * 160 * 2);
    short* WT1      = (short*)alloc((size_t)HC * 288 * 2);
    short* WT2      = (short*)alloc((size_t)HC * 288 * 2);
    short* fc1wT    = (short*)alloc((size_t)MLPc * 128 * 2);
    short* fc2wT    = (short*)alloc((size_t)NCc * 256 * 2);
    float* pooled   = (float*)alloc((size_t)Gg * HC * 4);
    short* prowb    = (short*)alloc((size_t)Gg * MLPc * 2);

    // csr_src lives in d_out (3.2 MB of 6.4 MB); dead before k_fc writes out
    int* csr_src = (int*)d_out;

    // ---- CSR build: rank co-runs with prep ----
    hipMemsetAsync(degi, 0, (size_t)Nn * 4, stream);
    k_mega<<<RANK_B + PREP_B, 256, 0, stream>>>(ei, degi, rank,
        W0, W1, W2, fc1w, fc2w, x_in,
        WT0, WT1, WT2, fc1wT, fc2wT, xb0, pooled);
    k_scan_block<<<NB, 256, 0, stream>>>(degi, rowptr, partials, Nn);
    k_scan_fin<<<NB, 256, 0, stream>>>(rowptr, partials);
    k_fill3<<<(Ee + 255) / 256, 256, 0, stream>>>(ei, rowptr, rank, ea, csr_src, eacsr);

    const int LGRID = (Mpad + 127) / 128;   // 391

    // ---- layer 0: gather (+EA reduce) then GEMM ----
    k_g0ea<<<G0_B + EA_B, 256, 0, stream>>>(rowptr, csr_src, xb0, eacsr, G, eab);
    k_layer_mfma<INC><<<LGRID, 256, 0, stream>>>(xb0, G, eab, WT0, degi,
        b0, g0, be0, rm0, rv0, xbA);

    // ---- layer 1 (in-place: layer reads only its own rows of xbA) ----
    k_gather<<<(Nn * (HC / 8) + 255) / 256, 256, 0, stream>>>(rowptr, csr_src, xbA, G);
    k_layer_mfma<HC><<<LGRID, 256, 0, stream>>>(xbA, G, eab, WT1, degi,
        b1, g1, be1, rm1, rv1, xbA);

    // ---- layer 2 ----
    k_gather<<<(Nn * (HC / 8) + 255) / 256, 256, 0, stream>>>(rowptr, csr_src, xbA, G);
    k_layer_mfma<HC><<<LGRID, 256, 0, stream>>>(xbA, G, eab, WT2, degi,
        b2, g2, be2, rm2, rv2, xb3);

    // ---- pool + Prow (pooled pre-zeroed in k_mega) ----
    k_pool2<<<((Nn + 63) / 64 * 32 + 255) / 256, 256, 0, stream>>>(xb3, batch, pooled);
    k_prow<<<Gg, 256, 0, stream>>>(pooled, fc1w, fc1b, prowb);

    // ---- fused fc1 + fc2 ----
    k_fc_mfma<<<(Mpad + 127) / 128, 512, 0, stream>>>(xb3, prowb, batch, fc1wT, fc2wT,
                                                      fc2b, (float*)d_out);
}